// Round 7
// baseline (260.290 us; speedup 1.0000x reference)
//
#include <hip/hip_runtime.h>
#include <math.h>
#include <stdint.h>

namespace {

typedef __attribute__((ext_vector_type(8))) short s8v;   // 8 bf16 (MFMA A/B frag)
typedef __attribute__((ext_vector_type(4))) float f4v;   // MFMA C/D frag
typedef unsigned short u16;

__device__ __forceinline__ float fexp2(float x) {  // native v_exp_f32 (2^x)
  return __builtin_amdgcn_exp2f(x);
}

__device__ __forceinline__ u16 f2bf(float f) {  // RTNE
  union { float f; uint32_t u; } v; v.f = f;
  uint32_t r = v.u + 0x7fffu + ((v.u >> 16) & 1u);
  return (u16)(r >> 16);
}
__device__ __forceinline__ float bf2f(u16 h) {
  union { uint32_t u; float f; } v; v.u = ((uint32_t)h) << 16;
  return v.f;
}
__device__ __forceinline__ uint32_t pk2r(float a, float b) {  // RTNE pair pack
  return (uint32_t)f2bf(a) | ((uint32_t)f2bf(b) << 16);
}
__device__ __forceinline__ uint32_t pk2(float a, float b) {  // fast round-half-up
  union { float f; uint32_t u; } x, y; x.f = a; y.f = b;
  return ((x.u + 0x8000u) >> 16) | ((y.u + 0x8000u) & 0xffff0000u);
}
__device__ __forceinline__ float sigmoidf_(float x) { return 1.0f / (1.0f + __expf(-x)); }

__device__ __forceinline__ void gload16(const u16* g, u16* l) {
  __builtin_amdgcn_global_load_lds(
      (const __attribute__((address_space(1))) void*)g,
      (__attribute__((address_space(3))) void*)l, 16, 0, 0);
}

// ---------------------------------------------------------------------------
// fp32 -> bf16 conversion; equal jobs of 262144 float4-groups.
// Blocks (y==0, x<4) additionally zero Vtot (16 KB) for qkv's atomic sums.
// ---------------------------------------------------------------------------
struct CvtJob { const float* src; u16* dst; };
struct CvtArgs { CvtJob j[18]; float* vz; };

__global__ __launch_bounds__(256) void cvt_kernel(CvtArgs a) {
  if (blockIdx.y == 0 && blockIdx.x < 4) {
    float4 z; z.x = 0.f; z.y = 0.f; z.z = 0.f; z.w = 0.f;
    ((float4*)a.vz)[blockIdx.x * 256 + threadIdx.x] = z;
  }
  const CvtJob jb = a.j[blockIdx.y];
  const int i = blockIdx.x * 256 + threadIdx.x;
  const float4 v = ((const float4*)jb.src)[i];
  uint2 pk;
  pk.x = pk2r(v.x, v.y);
  pk.y = pk2r(v.z, v.w);
  ((uint2*)jb.dst)[i] = pk;
}

// ---------------------------------------------------------------------------
// FUSED QKV projection, 2 blocks/CU (round-5 version, capped at ~49 us --
// declared done; see session journal).  384 thr = 6 waves, matrix-split.
// ---------------------------------------------------------------------------
__global__ __launch_bounds__(384, 3) void qkv_gemm(
    const u16* __restrict__ xb,
    const u16* __restrict__ Wqb, const u16* __restrict__ Wkb, const u16* __restrict__ Wvb,
    const float* __restrict__ bq, const float* __restrict__ bk, const float* __restrict__ bv,
    const u16* __restrict__ memb,
    u16* __restrict__ Qb, u16* __restrict__ Kb, u16* __restrict__ Vt,
    float* __restrict__ Vtot) {
  __shared__ __align__(16) u16 as_[2][4096];  // A: 128x32 per buf, swizzled
  __shared__ __align__(16) u16 bs_[2][6144];  // B: 3 mats x 64x32 per buf
  const int t = threadIdx.x;
  const int nb = blockIdx.x, mb = blockIdx.y;  // 16 x 32 grid
  const int m0 = mb * 128, n0 = nb * 64;
  const int l = t & 63, w = t >> 6;
  const int mat = w >> 1;                      // 0,0,1,1,2,2
  const int wm = w & 1;                        // row half
  const int lr = l & 15, lq = l >> 4;
  const int rh = lr >> 1;                      // lds-row within fragment
  const int rb4 = (lr & 1) << 2;               // chunk base from row parity
  const int bmat = mat * 2048;                 // B-matrix base in bs_ buffer

  const f4v fz = {0.f, 0.f, 0.f, 0.f};
  f4v acc[4][4];
#pragma unroll
  for (int i = 0; i < 4; ++i)
#pragma unroll
    for (int j = 0; j < 4; ++j) acc[i][j] = fz;

  // ---- staging decode (verified inverse-swizzle map) ----------------------
  const int sc0a = (t & 7) ^ ((t >> 3) & 7);
  const int sgrowa = (((t & 255) >> 3) << 1) + (sc0a >> 2);
  const int sgka = (sc0a & 3) << 3;
  const u16* ga0 = xb + (size_t)(m0 + sgrowa) * 1024 + sgka;
  const u16* ga1 = xb + (size_t)(m0 + 64 + sgrowa) * 1024 + sgka;
  const int tq1 = t & 255;                         // mat1 = t<256 ? 0 : 1
  const int tq2 = (t < 128) ? (t + 128) : (t - 128);  // mat2 = t<128 ? 1 : 2
  const u16* wb1 = (t < 256) ? Wqb : Wkb;
  const u16* wb2 = (t < 128) ? Wkb : Wvb;
  const int sc01 = (tq1 & 7) ^ ((tq1 >> 3) & 7);
  const int sc02 = (tq2 & 7) ^ ((tq2 >> 3) & 7);
  const u16* gb1 = wb1 + (size_t)(n0 + ((tq1 >> 3) << 1) + (sc01 >> 2)) * 1024 +
                   ((sc01 & 3) << 3);
  const u16* gb2 = wb2 + (size_t)(n0 + ((tq2 >> 3) << 1) + (sc02 >> 2)) * 1024 +
                   ((sc02 & 3) << 3);
  const int mb1 = ((t < 256) ? 0 : 2048) + tq1 * 8;
  const int mb2 = ((t < 128) ? 2048 : 4096) + tq2 * 8;

#define QKV_STAGE(c)                                                           \
  {                                                                            \
    const int ko_ = (c) * 32;                                                  \
    const int bb_ = (c) & 1;                                                   \
    if (t < 256) {                                                             \
      gload16(ga0 + ko_, &as_[bb_][(t & 255) * 8]);                            \
      gload16(ga1 + ko_, &as_[bb_][2048 + (t & 255) * 8]);                     \
    }                                                                          \
    gload16(gb1 + ko_, &bs_[bb_][mb1]);                                        \
    gload16(gb2 + ko_, &bs_[bb_][mb2]);                                        \
  }

  QKV_STAGE(0); QKV_STAGE(1);
  if (w < 4) {  // chunk 0 landed (wave-uniform outstanding counts)
    asm volatile("s_waitcnt vmcnt(4)" ::: "memory");
  } else {
    asm volatile("s_waitcnt vmcnt(2)" ::: "memory");
  }
  __builtin_amdgcn_s_barrier();

  const int co = ((rb4 + lq) ^ rh) * 8;
  for (int c = 0; c < 32; ++c) {
    const int cb = c & 1;
    s8v af[4], bf[4];
#pragma unroll
    for (int mi = 0; mi < 4; ++mi)
      af[mi] = *(const s8v*)(&as_[cb][(wm * 32 + mi * 8 + rh) * 64 + co]);
#pragma unroll
    for (int ni = 0; ni < 4; ++ni)
      bf[ni] = *(const s8v*)(&bs_[cb][bmat + (ni * 8 + rh) * 64 + co]);
    asm volatile("s_waitcnt lgkmcnt(0)" ::: "memory");  // own reads in regs
    __builtin_amdgcn_sched_barrier(0);
    __builtin_amdgcn_s_barrier();                // all waves done with buf cb
    if (c + 2 < 32) QKV_STAGE(c + 2);            // overwrite just-freed buf
    __builtin_amdgcn_s_setprio(1);
    if (mat < 2) {  // Q/K: swapped operands (C^T)
#pragma unroll
      for (int mi = 0; mi < 4; ++mi)
#pragma unroll
        for (int ni = 0; ni < 4; ++ni)
          acc[mi][ni] = __builtin_amdgcn_mfma_f32_16x16x32_bf16(
              bf[ni], af[mi], acc[mi][ni], 0, 0, 0);
    } else {        // V: normal operands
#pragma unroll
      for (int mi = 0; mi < 4; ++mi)
#pragma unroll
        for (int ni = 0; ni < 4; ++ni)
          acc[mi][ni] = __builtin_amdgcn_mfma_f32_16x16x32_bf16(
              af[mi], bf[ni], acc[mi][ni], 0, 0, 0);
    }
    __builtin_amdgcn_s_setprio(0);
    if (c + 2 < 32) {        // tile c+1 landed (c+2 still in flight)
      if (w < 4) {
        asm volatile("s_waitcnt vmcnt(4)" ::: "memory");
      } else {
        asm volatile("s_waitcnt vmcnt(2)" ::: "memory");
      }
    } else if (c == 30) {
      asm volatile("s_waitcnt vmcnt(0)" ::: "memory");
    }
    if (c < 31) __builtin_amdgcn_s_barrier();
  }
#undef QKV_STAGE
  __builtin_amdgcn_sched_barrier(0);  // keep epilogue loads out of the loop

  if (mat < 2) {
    // ---- Q/K epilogue (C^T layout) ---------------------------------------
    u16* dst = (mat == 0) ? Qb : Kb;
    const float* bias = (mat == 0) ? bq : bk;
#pragma unroll
    for (int mi = 0; mi < 4; ++mi)
#pragma unroll
      for (int ni = 0; ni < 4; ++ni) {
        const int m = m0 + wm * 64 + mi * 16 + lr;
        const int nb4 = n0 + ni * 16 + lq * 4;
        const float4 b4 = *(const float4*)&bias[nb4];
        uint2 pk;
        pk.x = pk2r(acc[mi][ni][0] + b4.x, acc[mi][ni][1] + b4.y);
        pk.y = pk2r(acc[mi][ni][2] + b4.z, acc[mi][ni][3] + b4.w);
        *(uint2*)(dst + (size_t)m * 1024 + nb4) = pk;
      }
  } else {
    // ---- V epilogue (normal layout): gate, transpose-store, Vtot atomics -
    const int b = m0 >> 10;
    float vpart[4] = {0.f, 0.f, 0.f, 0.f};
#pragma unroll
    for (int mi = 0; mi < 4; ++mi)
#pragma unroll
      for (int ni = 0; ni < 4; ++ni) {
        const int mrow = m0 + wm * 64 + mi * 16 + lq * 4;
        const int ncol = n0 + ni * 16 + lr;
        const int h = ncol >> 6, d = ncol & 63;
        const float bi = bv[ncol];
        float tv[4];
#pragma unroll
        for (int r = 0; r < 4; ++r)
          tv[r] = (acc[mi][ni][r] + bi) *
                  sigmoidf_(bf2f(memb[(size_t)(mrow + r) * 1024 + ncol]));
        vpart[ni] += (tv[0] + tv[1]) + (tv[2] + tv[3]);
        const int s = mrow & 1023;
        uint2 pk;
        pk.x = pk2r(tv[0], tv[1]);
        pk.y = pk2r(tv[2], tv[3]);
        *(uint2*)(Vt + ((size_t)((b * 16 + h) * 64 + d)) * 1024 + s) = pk;
      }
#pragma unroll
    for (int ni = 0; ni < 4; ++ni) {
      const int ncol = n0 + ni * 16 + lr;
      atomicAdd(&Vtot[(size_t)(b * 16 + (ncol >> 6)) * 64 + (ncol & 63)], vpart[ni]);
    }
  }
}

// ---------------------------------------------------------------------------
// 128(M) x 64(N) GEMM, qkv-proven per-wave geometry: 128 thr = 2 waves,
// each wave owns a full 64x64 tile (4x4 acc, 8 ds_reads, 16 MFMA per BK=32
// chunk -> MFMA:ds ratio 2.0).  LDS dbuf 2x(A 8KB + B 4KB) = 24 KB ->
// ~6 blocks/CU resident (multi-block phase overlap).  Grid (16,32) = 512
// blocks.  Per thread per chunk: 4 A + 2 B loads (vmcnt 6, dbuf distance 2).
// Schedule per chunk: ds_read 8 | lgkm0 | bar | stage c+2 | 16 MFMA
// (setprio) | vmcnt(6) | bar.  Swapped operands (C^T epilogue).
// MODE 0: out = A @ W^T + bias (fp32 out, float4 stores), K=1024
// MODE 1: gate: A = [Ab | A2b] (K=2048); out = Ab * sigmoid(A@Wg^T+bg) (bf16)
// ---------------------------------------------------------------------------
template <int MODE>
__global__ __launch_bounds__(128, 4) void gemm64(
    const u16* __restrict__ Ab, const u16* __restrict__ A2b,
    const u16* __restrict__ W, const float* __restrict__ bias,
    u16* __restrict__ outb, float* __restrict__ outf, int K) {
  __shared__ __align__(16) u16 as_[2][4096];  // A: 128x32 per buf (2 halves)
  __shared__ __align__(16) u16 bs_[2][2048];  // B: 64x32 per buf
  const int t = threadIdx.x;                  // 0..127
  const int m0 = blockIdx.y * 128, n0 = blockIdx.x * 64;
  const int l = t & 63, w = t >> 6;           // 2 waves: w = row half
  const int lr = l & 15, lq = l >> 4;
  const int rh = lr >> 1, rb4 = (lr & 1) << 2;
  const f4v fz = {0.f, 0.f, 0.f, 0.f};
  f4v acc[4][4];
#pragma unroll
  for (int i = 0; i < 4; ++i)
#pragma unroll
    for (int j = 0; j < 4; ++j) acc[i][j] = fz;

  // staging decode: thread t covers chunk ids {t, t+128} per 256-chunk half;
  // sc(t+128) == sc(t), so rows are gr1 + {0,32} (and +64,+96 for A half 1).
  const int sc1 = (t & 7) ^ ((t >> 3) & 7);
  const int gr1 = ((t >> 3) << 1) + (sc1 >> 2);
  const int gk1 = (sc1 & 3) << 3;
  const u16* gA = Ab + (size_t)(m0 + gr1) * 1024 + gk1;
  const u16* gA2 = (MODE == 1) ? (A2b + (size_t)(m0 + gr1) * 1024 + gk1) : gA;
  const u16* gW = W + (size_t)(n0 + gr1) * K + gk1;
  const size_t wstep = (size_t)32 * K;
  const int nc = K >> 5;

#define G_STAGE(c)                                                             \
  {                                                                            \
    const int c_ = (c);                                                        \
    const u16* ab_ = (MODE == 1 && c_ >= 32) ? gA2 : gA;                       \
    const int ko_ = ((MODE == 1 && c_ >= 32) ? (c_ - 32) : c_) * 32;           \
    const int bb_ = c_ & 1;                                                    \
    gload16(ab_ + ko_,             &as_[bb_][t * 8]);                          \
    gload16(ab_ + 32 * 1024 + ko_, &as_[bb_][(t + 128) * 8]);                  \
    gload16(ab_ + 64 * 1024 + ko_, &as_[bb_][2048 + t * 8]);                   \
    gload16(ab_ + 96 * 1024 + ko_, &as_[bb_][2048 + (t + 128) * 8]);           \
    gload16(gW + c_ * 32,          &bs_[bb_][t * 8]);                          \
    gload16(gW + wstep + c_ * 32,  &bs_[bb_][(t + 128) * 8]);                  \
  }

  G_STAGE(0); G_STAGE(1);
  asm volatile("s_waitcnt vmcnt(6)" ::: "memory");  // tile 0 landed
  __builtin_amdgcn_s_barrier();

  const int co = ((rb4 + lq) ^ rh) * 8;
  for (int c = 0; c < nc; ++c) {
    const int cb = c & 1;
    s8v af[4], bf[4];
#pragma unroll
    for (int mi = 0; mi < 4; ++mi)
      af[mi] = *(const s8v*)(&as_[cb][w * 2048 + (mi * 8 + rh) * 64 + co]);
#pragma unroll
    for (int ni = 0; ni < 4; ++ni)
      bf[ni] = *(const s8v*)(&bs_[cb][(ni * 8 + rh) * 64 + co]);
    asm volatile("s_waitcnt lgkmcnt(0)" ::: "memory");  // own reads in regs
    __builtin_amdgcn_sched_barrier(0);
    __builtin_amdgcn_s_barrier();                // all waves done with buf cb
    if (c + 2 < nc) G_STAGE(c + 2);              // overwrite just-freed buf
    __builtin_amdgcn_s_setprio(1);
#pragma unroll
    for (int mi = 0; mi < 4; ++mi)
#pragma unroll
      for (int ni = 0; ni < 4; ++ni)
        acc[mi][ni] = __builtin_amdgcn_mfma_f32_16x16x32_bf16(
            bf[ni], af[mi], acc[mi][ni], 0, 0, 0);
    __builtin_amdgcn_s_setprio(0);
    if (c + 2 < nc) {
      asm volatile("s_waitcnt vmcnt(6)" ::: "memory");   // tile c+1 landed
    } else if (c + 2 == nc) {
      asm volatile("s_waitcnt vmcnt(0)" ::: "memory");   // drain last tile
    }
    if (c + 1 < nc) __builtin_amdgcn_s_barrier();
  }
#undef G_STAGE
  __builtin_amdgcn_sched_barrier(0);  // keep epilogue loads out of the loop

  // ---- epilogue (C^T layout) ----------------------------------------------
#pragma unroll
  for (int mi = 0; mi < 4; ++mi)
#pragma unroll
    for (int ni = 0; ni < 4; ++ni) {
      const int m = m0 + w * 64 + mi * 16 + lr;
      const int nb4 = n0 + ni * 16 + lq * 4;
      const float4 b4 = *(const float4*)&bias[nb4];
      if (MODE == 0) {
        float4 o;
        o.x = acc[mi][ni][0] + b4.x; o.y = acc[mi][ni][1] + b4.y;
        o.z = acc[mi][ni][2] + b4.z; o.w = acc[mi][ni][3] + b4.w;
        *(float4*)(outf + (size_t)m * 1024 + nb4) = o;
      } else {
        const uint2 a2 = *(const uint2*)(Ab + (size_t)m * 1024 + nb4);
        float cx[4] = {bf2f((u16)(a2.x & 0xffff)), bf2f((u16)(a2.x >> 16)),
                       bf2f((u16)(a2.y & 0xffff)), bf2f((u16)(a2.y >> 16))};
        float g[4];
        g[0] = cx[0] * sigmoidf_(acc[mi][ni][0] + b4.x);
        g[1] = cx[1] * sigmoidf_(acc[mi][ni][1] + b4.y);
        g[2] = cx[2] * sigmoidf_(acc[mi][ni][2] + b4.z);
        g[3] = cx[3] * sigmoidf_(acc[mi][ni][3] + b4.w);
        uint2 pk;
        pk.x = pk2r(g[0], g[1]);
        pk.y = pk2r(g[2], g[3]);
        *(uint2*)(outb + (size_t)m * 1024 + nb4) = pk;
      }
    }
}

// ---------------------------------------------------------------------------
// MFMA flash attention with far-field truncation (round-10 structure).
// ---------------------------------------------------------------------------
__global__ __launch_bounds__(256) void attn_mfma(
    const u16* __restrict__ Qb, const u16* __restrict__ Kb,
    const u16* __restrict__ SPb, const u16* __restrict__ Vt,
    const float* __restrict__ tau, const float* __restrict__ Vtot,
    u16* __restrict__ CTXb) {
  __shared__ u16 kbuf[4096], skbuf[4096], vbuf[4096];
  __shared__ u16 pbuf[4][16 * 64];  // per-wave P[i][j], XOR-swizzled 16B chunks
  const int t = threadIdx.x, l = t & 63, w = t >> 6;
  const int lr = l & 15, lq = l >> 4;
  const int p = blockIdx.x;
  const int g = (p & 7) + 8 * (p >> 7);   // bh-group 0..63
  const int qt = (p >> 3) & 15;
  const int h = g & 15, b = g >> 4;

  const float tv_ = tau[h];
  const float c2 = 1.44269504088896f / tv_;     // log2e / tau
  const float K0 = 0.125f * 1.44269504088896f;  // scale * log2e
  int rad = (int)ceilf(tv_ * 0.171875f);  // 11/64: far scores <6e-5 -> P==1
  if (rad > 15) rad = 15;
  const int jlo = (qt - rad < 0) ? 0 : qt - rad;
  const int jhi = (qt + rad > 15) ? 15 : qt + rad;
  const int farCnt = 16 - (jhi - jlo + 1);

  float cN[4], cNi[4], cR[4], cRi[4];
#pragma unroll
  for (int i = 0; i < 4; ++i) {
    cN[i]  = fexp2(c2 * (float)(i * 16));
    cNi[i] = fexp2(-c2 * (float)(i * 16));
    cR[i]  = fexp2(c2 * (float)(lq * 4 + i));
    cRi[i] = fexp2(-c2 * (float)(lq * 4 + i));
  }

  s8v qf[2], sf[2];
  {
    const size_t base = ((size_t)(b * 1024 + qt * 64 + w * 16 + lr)) * 1024 + h * 64 + lq * 8;
    qf[0] = *(const s8v*)(Qb + base);
    qf[1] = *(const s8v*)(Qb + base + 32);
    sf[0] = *(const s8v*)(SPb + base);
    sf[1] = *(const s8v*)(SPb + base + 32);
  }
  const s8v ones = {0x3F80, 0x3F80, 0x3F80, 0x3F80, 0x3F80, 0x3F80, 0x3F80, 0x3F80};

  const f4v fz = {0.f, 0.f, 0.f, 0.f};
  f4v oacc[4], vs[4];
  float lacc[4];
#pragma unroll
  for (int i = 0; i < 4; ++i) { oacc[i] = fz; vs[i] = fz; lacc[i] = 0.f; }

  const int iqw = qt * 64 + w * 16;      // wave q-base
  const int srow = t >> 3;
  const int csw = ((t & 7) ^ (srow & 7)) * 8;  // staged global chunk (swizzle)
  const int rx = lr & 7;
  u16* pw = pbuf[w];

  for (int jc = jlo; jc <= jhi; ++jc) {
    const int j0 = jc * 64;
    __syncthreads();  // all waves done with previous chunk's LDS
    {
      const size_t kg = ((size_t)(b * 1024 + j0 + srow)) * 1024 + h * 64 + csw;
      gload16(Kb + kg, kbuf + t * 8);
      gload16(Kb + kg + 32 * 1024, kbuf + 2048 + t * 8);
      gload16(SPb + kg, skbuf + t * 8);
      gload16(SPb + kg + 32 * 1024, skbuf + 2048 + t * 8);
      const size_t vg = ((size_t)((b * 16 + h) * 64 + srow)) * 1024 + j0 + csw;
      gload16(Vt + vg, vbuf + t * 8);
      gload16(Vt + vg + 32 * 1024, vbuf + 2048 + t * 8);
    }
    __syncthreads();

    // ---- S^T: mfma(K-rows, Q-cols) -> C[j=ni*16+lq*4+r][i=lr] ------------
    f4v sa[4], ssa[4];
#pragma unroll
    for (int ni = 0; ni < 4; ++ni) { sa[ni] = fz; ssa[ni] = fz; }
#pragma unroll
    for (int ks = 0; ks < 2; ++ks) {
#pragma unroll
      for (int ni = 0; ni < 4; ++ni) {
        const int off = (ni * 16 + lr) * 64 + (((ks * 4 + lq) ^ rx) * 8);
        const s8v kf = *(const s8v*)(kbuf + off);
        sa[ni] = __builtin_amdgcn_mfma_f32_16x16x32_bf16(kf, qf[ks], sa[ni], 0, 0, 0);
        const s8v skf = *(const s8v*)(skbuf + off);
        ssa[ni] = __builtin_amdgcn_mfma_f32_16x16x32_bf16(skf, sf[ks], ssa[ni], 0, 0, 0);
      }
    }

    // ---- score modifiers + exp (no max subtraction) ----------------------
    const int D0 = iqw - j0;  // i - j = D0 + lr - j_loc
    float pv[4][4];
    if (jc < qt) {            // strictly below diagonal: i > j
      const float EA = K0 * fexp2(-c2 * (float)(D0 + lr));
#pragma unroll
      for (int ni = 0; ni < 4; ++ni)
#pragma unroll
        for (int r = 0; r < 4; ++r) {
          const float t1 = fmaf(ssa[ni][r], 0.125f, 1.0f);
          const float e = fexp2(sa[ni][r] * cN[ni] * cR[r] * EA * t1);
          pv[ni][r] = e;
          lacc[ni] += e;
        }
    } else if (jc > qt) {     // strictly above diagonal: i < j
      const float EAi = K0 * fexp2(c2 * (float)(D0 + lr));
#pragma unroll
      for (int ni = 0; ni < 4; ++ni)
#pragma unroll
        for (int r = 0; r < 4; ++r) {
          const float t1 = fmaf(ssa[ni][r], 0.125f, 1.0f);
          const float e = fexp2(sa[ni][r] * cNi[ni] * cRi[r] * EAi * t1);
          pv[ni][r] = e;
          lacc[ni] += e;
        }
    } else {                  // diagonal chunk: per-element side select
      const float EA  = K0 * fexp2(-c2 * (float)(D0 + lr));
      const float EAi = K0 * fexp2(c2 * (float)(D0 + lr));
#pragma unroll
      for (int ni = 0; ni < 4; ++ni)
#pragma unroll
        for (int r = 0; r < 4; ++r) {
          const int jloc = ni * 16 + lq * 4 + r;
          const float fb = cN[ni] * cR[r] * EA;
          const float fa = cNi[ni] * cRi[r] * EAi;
          const float f = (D0 + lr >= jloc) ? fb : fa;
          const float t1 = fmaf(ssa[ni][r], 0.125f, 1.0f);
          const float e = fexp2(sa[ni][r] * f * t1);
          pv[ni][r] = e;
          lacc[ni] += e;
        }
    }

    // ---- P[i][j] to LDS (b64 writes, XOR-swizzled chunks) ----------------
#pragma unroll
    for (int ni = 0; ni < 4; ++ni) {
      const int phys = (ni * 2 + (lq >> 1)) ^ rx;
      uint2 p2;
      p2.x = pk2(pv[ni][0], pv[ni][1]);
      p2.y = pk2(pv[ni][2], pv[ni][3]);
      *(uint2*)(pw + lr * 64 + phys * 8 + (lq & 1) * 4) = p2;
    }

    // ---- O^T += V^T @ P^T; vs += V^T @ ones (near-V column sums) ---------
#pragma unroll
    for (int ks = 0; ks < 2; ++ks) {
      const s8v pf = *(const s8v*)(pw + lr * 64 + (((ks * 4 + lq) ^ rx) * 8));
#pragma unroll
      for (int nd = 0; nd < 4; ++nd) {
        const int off = (nd * 16 + lr) * 64 + (((ks * 4 + lq) ^ rx) * 8);
        const s8v vf = *(const s8v*)(vbuf + off);
        oacc[nd] = __builtin_amdgcn_mfma_f32_16x16x32_bf16(vf, pf, oacc[nd], 0, 0, 0);
        vs[nd] = __builtin_amdgcn_mfma_f32_16x16x32_bf16(vf, ones, vs[nd], 0, 0, 0);
      }
    }
  }

  // ---- far field: oacc += Vtot - nearV; l += 64*farCnt; store ------------
  float ls = (lacc[0] + lacc[1]) + (lacc[2] + lacc[3]);
  ls += __shfl_xor(ls, 16);
  ls += __shfl_xor(ls, 32);
  ls += 64.0f * (float)farCnt;
  const float inv = 1.0f / ls;
  const float* vt0 = Vtot + (size_t)(b * 16 + h) * 64;
  const size_t orow = ((size_t)(b * 1024 + qt * 64 + w * 16 + lr)) * 1024 + h * 64;
#pragma unroll
  for (int nd = 0; nd < 4; ++nd) {
    const float4 vt4 = *(const float4*)(vt0 + nd * 16 + lq * 4);
    float o0 = (oacc[nd][0] + vt4.x - vs[nd][0]) * inv;
    float o1 = (oacc[nd][1] + vt4.y - vs[nd][1]) * inv;
    float o2 = (oacc[nd][2] + vt4.z - vs[nd][2]) * inv;
    float o3 = (oacc[nd][3] + vt4.w - vs[nd][3]) * inv;
    uint2 o;
    o.x = pk2r(o0, o1);
    o.y = pk2r(o2, o3);
    *(uint2*)(CTXb + orow + nd * 16 + lq * 4) = o;
  }
}

}  // namespace

extern "C" void kernel_launch(void* const* d_in, const int* in_sizes, int n_in,
                              void* d_out, int out_size, void* d_ws, size_t ws_size,
                              hipStream_t stream) {
  const float* x      = (const float*)d_in[0];
  const float* spikes = (const float*)d_in[1];
  const float* mem    = (const float*)d_in[2];
  const float* Wq     = (const float*)d_in[3];
  const float* bq     = (const float*)d_in[4];
  const float* Wk     = (const float*)d_in[5];
  const float* bk     = (const float*)d_in[6];
  const float* Wv     = (const float*)d_in[7];
  const float* bv     = (const float*)d_in[8];
  const float* Wo     = (const float*)d_in[9];
  const float* bo     = (const float*)d_in[10];
  const float* tau    = (const float*)d_in[11];
  const float* Wg     = (const float*)d_in[12];
  const float* bg     = (const float*)d_in[13];
  float* out = (float*)d_out;

  uint8_t* w8 = (uint8_t*)d_ws;
  u16* spb  = (u16*)(w8);                 // 8 MB
  u16* xb   = (u16*)(w8 + (8u << 20));    // 8 MB
  u16* Wqb  = (u16*)(w8 + (16u << 20));   // 2 MB
  u16* Wkb  = (u16*)(w8 + (18u << 20));   // 2 MB
  u16* Wvb  = (u16*)(w8 + (20u << 20));   // 2 MB
  u16* Wob  = (u16*)(w8 + (22u << 20));   // 2 MB
  u16* Wgb  = (u16*)(w8 + (24u << 20));   // 4 MB
  u16* Qb   = (u16*)(w8 + (28u << 20));   // 8 MB
  u16* Kb   = (u16*)(w8 + (36u << 20));   // 8 MB
  u16* Vt   = (u16*)(w8 + (44u << 20));   // 8 MB  [b,h,d,s]
  u16* CTXb = (u16*)(w8 + (52u << 20));   // 8 MB
  float* Vtot = (float*)(w8 + (60u << 20));  // 16 KB
  u16* memb = (u16*)d_out;  // 8 MB of the 16 MB fp32 out buffer; dead until
                            // the final out_gemm overwrites it
  u16* gctx = xb;           // x dead after QKV

  // 1) bf16 conversions (18 jobs) + Vtot zeroing (4 spare blocks)
  constexpr size_t QE = 262144 * 4;  // elements per job
  CvtArgs ca;
  for (int q = 0; q < 4; ++q) ca.j[q]     = {x + q * QE,      xb + q * QE};
  for (int q = 0; q < 4; ++q) ca.j[4 + q] = {spikes + q * QE, spb + q * QE};
  for (int q = 0; q < 4; ++q) ca.j[8 + q] = {mem + q * QE,    memb + q * QE};
  ca.j[12] = {Wq, Wqb};
  ca.j[13] = {Wk, Wkb};
  ca.j[14] = {Wv, Wvb};
  ca.j[15] = {Wo, Wob};
  ca.j[16] = {Wg, Wgb};
  ca.j[17] = {Wg + QE, Wgb + QE};
  ca.vz = Vtot;
  cvt_kernel<<<dim3(1024, 18), 256, 0, stream>>>(ca);

  // 2) FUSED QKV projection (round-5 version, capped)
  qkv_gemm<<<dim3(16, 32), 384, 0, stream>>>(xb, Wqb, Wkb, Wvb, bq, bk, bv, memb,
                                             Qb, Kb, Vt, Vtot);
  // 3) flash attention (near chunks + far-field closed form, XCD swizzle)
  attn_mfma<<<dim3(1024), 256, 0, stream>>>(Qb, Kb, spb, Vt, tau, Vtot, CTXb);
  // 4) dendritic gate (K=2048 concat; mem-bf16 lives in d_out) -- new
  //    128-thr/2-wave/64x64-per-wave geometry, 512 blocks (~6/CU resident)
  gemm64<1><<<dim3(16, 32), 128, 0, stream>>>(CTXb, memb, Wgb, bg, gctx, nullptr, 2048);
  // 5) output projection (fp32 out; overwrites memb region last)
  gemm64<0><<<dim3(16, 32), 128, 0, stream>>>(gctx, nullptr, Wob, bo, nullptr, out, 1024);
}

// Round 8
// 243.492 us; speedup vs baseline: 1.0690x; 1.0690x over previous
//
#include <hip/hip_runtime.h>
#include <math.h>
#include <stdint.h>

namespace {

typedef __attribute__((ext_vector_type(8))) short s8v;   // 8 bf16 (MFMA A/B frag)
typedef __attribute__((ext_vector_type(4))) float f4v;   // MFMA C/D frag
typedef unsigned short u16;

__device__ __forceinline__ float fexp2(float x) {  // native v_exp_f32 (2^x)
  return __builtin_amdgcn_exp2f(x);
}

__device__ __forceinline__ u16 f2bf(float f) {  // RTNE
  union { float f; uint32_t u; } v; v.f = f;
  uint32_t r = v.u + 0x7fffu + ((v.u >> 16) & 1u);
  return (u16)(r >> 16);
}
__device__ __forceinline__ float bf2f(u16 h) {
  union { uint32_t u; float f; } v; v.u = ((uint32_t)h) << 16;
  return v.f;
}
__device__ __forceinline__ uint32_t pk2r(float a, float b) {  // RTNE pair pack
  return (uint32_t)f2bf(a) | ((uint32_t)f2bf(b) << 16);
}
__device__ __forceinline__ uint32_t pk2(float a, float b) {  // fast round-half-up
  union { float f; uint32_t u; } x, y; x.f = a; y.f = b;
  return ((x.u + 0x8000u) >> 16) | ((y.u + 0x8000u) & 0xffff0000u);
}
__device__ __forceinline__ float sigmoidf_(float x) { return 1.0f / (1.0f + __expf(-x)); }

__device__ __forceinline__ void gload16(const u16* g, u16* l) {
  __builtin_amdgcn_global_load_lds(
      (const __attribute__((address_space(1))) void*)g,
      (__attribute__((address_space(3))) void*)l, 16, 0, 0);
}

// ---------------------------------------------------------------------------
// fp32 -> bf16 conversion; equal jobs of 262144 float4-groups.
// Blocks (y==0, x<4) additionally zero Vtot (16 KB) for qkv's atomic sums.
// ---------------------------------------------------------------------------
struct CvtJob { const float* src; u16* dst; };
struct CvtArgs { CvtJob j[18]; float* vz; };

__global__ __launch_bounds__(256) void cvt_kernel(CvtArgs a) {
  if (blockIdx.y == 0 && blockIdx.x < 4) {
    float4 z; z.x = 0.f; z.y = 0.f; z.z = 0.f; z.w = 0.f;
    ((float4*)a.vz)[blockIdx.x * 256 + threadIdx.x] = z;
  }
  const CvtJob jb = a.j[blockIdx.y];
  const int i = blockIdx.x * 256 + threadIdx.x;
  const float4 v = ((const float4*)jb.src)[i];
  uint2 pk;
  pk.x = pk2r(v.x, v.y);
  pk.y = pk2r(v.z, v.w);
  ((uint2*)jb.dst)[i] = pk;
}

// ---------------------------------------------------------------------------
// FUSED QKV projection, 2 blocks/CU (round-5 version, capped at ~49 us --
// declared done; see session journal).  384 thr = 6 waves, matrix-split.
// ---------------------------------------------------------------------------
__global__ __launch_bounds__(384, 3) void qkv_gemm(
    const u16* __restrict__ xb,
    const u16* __restrict__ Wqb, const u16* __restrict__ Wkb, const u16* __restrict__ Wvb,
    const float* __restrict__ bq, const float* __restrict__ bk, const float* __restrict__ bv,
    const u16* __restrict__ memb,
    u16* __restrict__ Qb, u16* __restrict__ Kb, u16* __restrict__ Vt,
    float* __restrict__ Vtot) {
  __shared__ __align__(16) u16 as_[2][4096];  // A: 128x32 per buf, swizzled
  __shared__ __align__(16) u16 bs_[2][6144];  // B: 3 mats x 64x32 per buf
  const int t = threadIdx.x;
  const int nb = blockIdx.x, mb = blockIdx.y;  // 16 x 32 grid
  const int m0 = mb * 128, n0 = nb * 64;
  const int l = t & 63, w = t >> 6;
  const int mat = w >> 1;                      // 0,0,1,1,2,2
  const int wm = w & 1;                        // row half
  const int lr = l & 15, lq = l >> 4;
  const int rh = lr >> 1;                      // lds-row within fragment
  const int rb4 = (lr & 1) << 2;               // chunk base from row parity
  const int bmat = mat * 2048;                 // B-matrix base in bs_ buffer

  const f4v fz = {0.f, 0.f, 0.f, 0.f};
  f4v acc[4][4];
#pragma unroll
  for (int i = 0; i < 4; ++i)
#pragma unroll
    for (int j = 0; j < 4; ++j) acc[i][j] = fz;

  // ---- staging decode (verified inverse-swizzle map) ----------------------
  const int sc0a = (t & 7) ^ ((t >> 3) & 7);
  const int sgrowa = (((t & 255) >> 3) << 1) + (sc0a >> 2);
  const int sgka = (sc0a & 3) << 3;
  const u16* ga0 = xb + (size_t)(m0 + sgrowa) * 1024 + sgka;
  const u16* ga1 = xb + (size_t)(m0 + 64 + sgrowa) * 1024 + sgka;
  const int tq1 = t & 255;                         // mat1 = t<256 ? 0 : 1
  const int tq2 = (t < 128) ? (t + 128) : (t - 128);  // mat2 = t<128 ? 1 : 2
  const u16* wb1 = (t < 256) ? Wqb : Wkb;
  const u16* wb2 = (t < 128) ? Wkb : Wvb;
  const int sc01 = (tq1 & 7) ^ ((tq1 >> 3) & 7);
  const int sc02 = (tq2 & 7) ^ ((tq2 >> 3) & 7);
  const u16* gb1 = wb1 + (size_t)(n0 + ((tq1 >> 3) << 1) + (sc01 >> 2)) * 1024 +
                   ((sc01 & 3) << 3);
  const u16* gb2 = wb2 + (size_t)(n0 + ((tq2 >> 3) << 1) + (sc02 >> 2)) * 1024 +
                   ((sc02 & 3) << 3);
  const int mb1 = ((t < 256) ? 0 : 2048) + tq1 * 8;
  const int mb2 = ((t < 128) ? 2048 : 4096) + tq2 * 8;

#define QKV_STAGE(c)                                                           \
  {                                                                            \
    const int ko_ = (c) * 32;                                                  \
    const int bb_ = (c) & 1;                                                   \
    if (t < 256) {                                                             \
      gload16(ga0 + ko_, &as_[bb_][(t & 255) * 8]);                            \
      gload16(ga1 + ko_, &as_[bb_][2048 + (t & 255) * 8]);                     \
    }                                                                          \
    gload16(gb1 + ko_, &bs_[bb_][mb1]);                                        \
    gload16(gb2 + ko_, &bs_[bb_][mb2]);                                        \
  }

  QKV_STAGE(0); QKV_STAGE(1);
  if (w < 4) {  // chunk 0 landed (wave-uniform outstanding counts)
    asm volatile("s_waitcnt vmcnt(4)" ::: "memory");
  } else {
    asm volatile("s_waitcnt vmcnt(2)" ::: "memory");
  }
  __builtin_amdgcn_s_barrier();

  const int co = ((rb4 + lq) ^ rh) * 8;
  for (int c = 0; c < 32; ++c) {
    const int cb = c & 1;
    s8v af[4], bf[4];
#pragma unroll
    for (int mi = 0; mi < 4; ++mi)
      af[mi] = *(const s8v*)(&as_[cb][(wm * 32 + mi * 8 + rh) * 64 + co]);
#pragma unroll
    for (int ni = 0; ni < 4; ++ni)
      bf[ni] = *(const s8v*)(&bs_[cb][bmat + (ni * 8 + rh) * 64 + co]);
    asm volatile("s_waitcnt lgkmcnt(0)" ::: "memory");  // own reads in regs
    __builtin_amdgcn_sched_barrier(0);
    __builtin_amdgcn_s_barrier();                // all waves done with buf cb
    if (c + 2 < 32) QKV_STAGE(c + 2);            // overwrite just-freed buf
    __builtin_amdgcn_s_setprio(1);
    if (mat < 2) {  // Q/K: swapped operands (C^T)
#pragma unroll
      for (int mi = 0; mi < 4; ++mi)
#pragma unroll
        for (int ni = 0; ni < 4; ++ni)
          acc[mi][ni] = __builtin_amdgcn_mfma_f32_16x16x32_bf16(
              bf[ni], af[mi], acc[mi][ni], 0, 0, 0);
    } else {        // V: normal operands
#pragma unroll
      for (int mi = 0; mi < 4; ++mi)
#pragma unroll
        for (int ni = 0; ni < 4; ++ni)
          acc[mi][ni] = __builtin_amdgcn_mfma_f32_16x16x32_bf16(
              af[mi], bf[ni], acc[mi][ni], 0, 0, 0);
    }
    __builtin_amdgcn_s_setprio(0);
    if (c + 2 < 32) {        // tile c+1 landed (c+2 still in flight)
      if (w < 4) {
        asm volatile("s_waitcnt vmcnt(4)" ::: "memory");
      } else {
        asm volatile("s_waitcnt vmcnt(2)" ::: "memory");
      }
    } else if (c == 30) {
      asm volatile("s_waitcnt vmcnt(0)" ::: "memory");
    }
    if (c < 31) __builtin_amdgcn_s_barrier();
  }
#undef QKV_STAGE
  __builtin_amdgcn_sched_barrier(0);  // keep epilogue loads out of the loop

  if (mat < 2) {
    // ---- Q/K epilogue (C^T layout) ---------------------------------------
    u16* dst = (mat == 0) ? Qb : Kb;
    const float* bias = (mat == 0) ? bq : bk;
#pragma unroll
    for (int mi = 0; mi < 4; ++mi)
#pragma unroll
      for (int ni = 0; ni < 4; ++ni) {
        const int m = m0 + wm * 64 + mi * 16 + lr;
        const int nb4 = n0 + ni * 16 + lq * 4;
        const float4 b4 = *(const float4*)&bias[nb4];
        uint2 pk;
        pk.x = pk2r(acc[mi][ni][0] + b4.x, acc[mi][ni][1] + b4.y);
        pk.y = pk2r(acc[mi][ni][2] + b4.z, acc[mi][ni][3] + b4.w);
        *(uint2*)(dst + (size_t)m * 1024 + nb4) = pk;
      }
  } else {
    // ---- V epilogue (normal layout): gate, transpose-store, Vtot atomics -
    const int b = m0 >> 10;
    float vpart[4] = {0.f, 0.f, 0.f, 0.f};
#pragma unroll
    for (int mi = 0; mi < 4; ++mi)
#pragma unroll
      for (int ni = 0; ni < 4; ++ni) {
        const int mrow = m0 + wm * 64 + mi * 16 + lq * 4;
        const int ncol = n0 + ni * 16 + lr;
        const int h = ncol >> 6, d = ncol & 63;
        const float bi = bv[ncol];
        float tv[4];
#pragma unroll
        for (int r = 0; r < 4; ++r)
          tv[r] = (acc[mi][ni][r] + bi) *
                  sigmoidf_(bf2f(memb[(size_t)(mrow + r) * 1024 + ncol]));
        vpart[ni] += (tv[0] + tv[1]) + (tv[2] + tv[3]);
        const int s = mrow & 1023;
        uint2 pk;
        pk.x = pk2r(tv[0], tv[1]);
        pk.y = pk2r(tv[2], tv[3]);
        *(uint2*)(Vt + ((size_t)((b * 16 + h) * 64 + d)) * 1024 + s) = pk;
      }
#pragma unroll
    for (int ni = 0; ni < 4; ++ni) {
      const int ncol = n0 + ni * 16 + lr;
      atomicAdd(&Vtot[(size_t)(b * 16 + (ncol >> 6)) * 64 + (ncol & 63)], vpart[ni]);
    }
  }
}

// ---------------------------------------------------------------------------
// 64(M) x 128(N) GEMM, BK=64, swizzled LDS, dbuf, counted-vmcnt pipeline
// (6 loads/tile -> vmcnt(6)), swapped operands.  [R1/R2 version -- best
// measured: inside the 248.3 us total.  v2 (512thr fine-phase) = +6.5 us,
// v3 (128thr 2-wave) = +16.5 us; resident-wave count + staging burst width
// beat per-wave MFMA:ds ratio for these small-K GEMMs.]
// MODE 0: out = A @ W^T + bias (fp32 out, float4 stores)
// MODE 1: gate: A = [Ab | A2b] (K=2048); out = Ab * sigmoid(A@Wg^T+bg) (bf16)
// ---------------------------------------------------------------------------
template <int MODE>
__global__ __launch_bounds__(256) void gemm64(
    const u16* __restrict__ Ab, const u16* __restrict__ A2b,
    const u16* __restrict__ W, const float* __restrict__ bias,
    u16* __restrict__ outb, float* __restrict__ outf, int K) {
  __shared__ __align__(16) u16 as_[8192], bs_[16384];  // 2 x (64x64 / 128x64), swizzled
  const int t = threadIdx.x, l = t & 63, w = t >> 6;
  const int wm = w >> 1, wn = w & 1, lr = l & 15, lq = l >> 4;
  const int m0 = blockIdx.y * 64, n0 = blockIdx.x * 128;
  const f4v fz = {0.f, 0.f, 0.f, 0.f};
  f4v acc[2][4];
#pragma unroll
  for (int i = 0; i < 2; ++i)
#pragma unroll
    for (int j = 0; j < 4; ++j) acc[i][j] = fz;
  const int rx = lr & 7;
  const int srow = t >> 3;
  const int scol = ((t & 7) ^ (srow & 7)) * 8;
  const int nc = K >> 6;

#define G64_STAGE(k0, bsel)                                                    \
  {                                                                            \
    const int kk_ = (k0);                                                      \
    const u16* Ae_ = Ab;                                                       \
    int ka_ = kk_;                                                             \
    if (MODE == 1 && kk_ >= 1024) { Ae_ = A2b; ka_ = kk_ - 1024; }             \
    _Pragma("unroll") for (int u = 0; u < 2; ++u)                              \
        gload16(Ae_ + (size_t)(m0 + u * 32 + srow) * 1024 + ka_ + scol,        \
                as_ + (bsel) * 4096 + u * 2048 + t * 8);                       \
    _Pragma("unroll") for (int u = 0; u < 4; ++u)                              \
        gload16(W + (size_t)(n0 + u * 32 + srow) * K + kk_ + scol,             \
                bs_ + (bsel) * 8192 + u * 2048 + t * 8);                       \
  }

  G64_STAGE(0, 0);   // tile 0: 6 loads
  G64_STAGE(64, 1);  // tile 1: 6 loads  (nc >= 16 always)
  asm volatile("s_waitcnt vmcnt(6)" ::: "memory");  // tile 0 landed
  __builtin_amdgcn_s_barrier();

  for (int c = 0; c < nc; ++c) {
    const int pp = c & 1;
    const int loA = pp * 4096, loB = pp * 8192;
    s8v af[2][2], bf[2][4];
#pragma unroll
    for (int ks = 0; ks < 2; ++ks) {
      const int co = ((ks * 4 + lq) ^ rx) * 8;
#pragma unroll
      for (int mi = 0; mi < 2; ++mi)
        af[ks][mi] = *(const s8v*)(as_ + loA + (wm * 32 + mi * 16 + lr) * 64 + co);
#pragma unroll
      for (int ni = 0; ni < 4; ++ni)
        bf[ks][ni] = *(const s8v*)(bs_ + loB + (wn * 64 + ni * 16 + lr) * 64 + co);
    }
    asm volatile("s_waitcnt lgkmcnt(0)" ::: "memory");
    __builtin_amdgcn_sched_barrier(0);
    __builtin_amdgcn_s_barrier();                     // all waves done with buf pp
    if (c + 2 < nc) G64_STAGE((c + 2) << 6, pp);      // flies across barriers
    __builtin_amdgcn_s_setprio(1);
#pragma unroll
    for (int ks = 0; ks < 2; ++ks)
#pragma unroll
      for (int mi = 0; mi < 2; ++mi)
#pragma unroll
        for (int ni = 0; ni < 4; ++ni)
          acc[mi][ni] = __builtin_amdgcn_mfma_f32_16x16x32_bf16(
              bf[ks][ni], af[ks][mi], acc[mi][ni], 0, 0, 0);
    __builtin_amdgcn_s_setprio(0);
    if (c + 2 < nc) {
      asm volatile("s_waitcnt vmcnt(6)" ::: "memory");  // tile c+1 done
    } else if (c + 1 < nc) {
      asm volatile("s_waitcnt vmcnt(0)" ::: "memory");  // drain last tile
    }
    if (c + 1 < nc) __builtin_amdgcn_s_barrier();
  }
  __builtin_amdgcn_sched_barrier(0);  // keep epilogue loads out of the loop
#undef G64_STAGE

#pragma unroll
  for (int mi = 0; mi < 2; ++mi)
#pragma unroll
    for (int ni = 0; ni < 4; ++ni) {
      const int m = m0 + wm * 32 + mi * 16 + lr;
      const int nb4 = n0 + wn * 64 + ni * 16 + lq * 4;
      const float4 b4 = *(const float4*)&bias[nb4];
      if (MODE == 0) {
        float4 o;
        o.x = acc[mi][ni][0] + b4.x; o.y = acc[mi][ni][1] + b4.y;
        o.z = acc[mi][ni][2] + b4.z; o.w = acc[mi][ni][3] + b4.w;
        *(float4*)(outf + (size_t)m * 1024 + nb4) = o;
      } else {
        const uint2 a2 = *(const uint2*)(Ab + (size_t)m * 1024 + nb4);
        float cx[4] = {bf2f((u16)(a2.x & 0xffff)), bf2f((u16)(a2.x >> 16)),
                       bf2f((u16)(a2.y & 0xffff)), bf2f((u16)(a2.y >> 16))};
        float g[4];
        g[0] = cx[0] * sigmoidf_(acc[mi][ni][0] + b4.x);
        g[1] = cx[1] * sigmoidf_(acc[mi][ni][1] + b4.y);
        g[2] = cx[2] * sigmoidf_(acc[mi][ni][2] + b4.z);
        g[3] = cx[3] * sigmoidf_(acc[mi][ni][3] + b4.w);
        uint2 pk;
        pk.x = pk2r(g[0], g[1]);
        pk.y = pk2r(g[2], g[3]);
        *(uint2*)(outb + (size_t)m * 1024 + nb4) = pk;
      }
    }
}

// ---------------------------------------------------------------------------
// MFMA flash attention with far-field truncation (round-10 structure).
// ---------------------------------------------------------------------------
__global__ __launch_bounds__(256) void attn_mfma(
    const u16* __restrict__ Qb, const u16* __restrict__ Kb,
    const u16* __restrict__ SPb, const u16* __restrict__ Vt,
    const float* __restrict__ tau, const float* __restrict__ Vtot,
    u16* __restrict__ CTXb) {
  __shared__ u16 kbuf[4096], skbuf[4096], vbuf[4096];
  __shared__ u16 pbuf[4][16 * 64];  // per-wave P[i][j], XOR-swizzled 16B chunks
  const int t = threadIdx.x, l = t & 63, w = t >> 6;
  const int lr = l & 15, lq = l >> 4;
  const int p = blockIdx.x;
  const int g = (p & 7) + 8 * (p >> 7);   // bh-group 0..63
  const int qt = (p >> 3) & 15;
  const int h = g & 15, b = g >> 4;

  const float tv_ = tau[h];
  const float c2 = 1.44269504088896f / tv_;     // log2e / tau
  const float K0 = 0.125f * 1.44269504088896f;  // scale * log2e
  int rad = (int)ceilf(tv_ * 0.171875f);  // 11/64: far scores <6e-5 -> P==1
  if (rad > 15) rad = 15;
  const int jlo = (qt - rad < 0) ? 0 : qt - rad;
  const int jhi = (qt + rad > 15) ? 15 : qt + rad;
  const int farCnt = 16 - (jhi - jlo + 1);

  float cN[4], cNi[4], cR[4], cRi[4];
#pragma unroll
  for (int i = 0; i < 4; ++i) {
    cN[i]  = fexp2(c2 * (float)(i * 16));
    cNi[i] = fexp2(-c2 * (float)(i * 16));
    cR[i]  = fexp2(c2 * (float)(lq * 4 + i));
    cRi[i] = fexp2(-c2 * (float)(lq * 4 + i));
  }

  s8v qf[2], sf[2];
  {
    const size_t base = ((size_t)(b * 1024 + qt * 64 + w * 16 + lr)) * 1024 + h * 64 + lq * 8;
    qf[0] = *(const s8v*)(Qb + base);
    qf[1] = *(const s8v*)(Qb + base + 32);
    sf[0] = *(const s8v*)(SPb + base);
    sf[1] = *(const s8v*)(SPb + base + 32);
  }
  const s8v ones = {0x3F80, 0x3F80, 0x3F80, 0x3F80, 0x3F80, 0x3F80, 0x3F80, 0x3F80};

  const f4v fz = {0.f, 0.f, 0.f, 0.f};
  f4v oacc[4], vs[4];
  float lacc[4];
#pragma unroll
  for (int i = 0; i < 4; ++i) { oacc[i] = fz; vs[i] = fz; lacc[i] = 0.f; }

  const int iqw = qt * 64 + w * 16;      // wave q-base
  const int srow = t >> 3;
  const int csw = ((t & 7) ^ (srow & 7)) * 8;  // staged global chunk (swizzle)
  const int rx = lr & 7;
  u16* pw = pbuf[w];

  for (int jc = jlo; jc <= jhi; ++jc) {
    const int j0 = jc * 64;
    __syncthreads();  // all waves done with previous chunk's LDS
    {
      const size_t kg = ((size_t)(b * 1024 + j0 + srow)) * 1024 + h * 64 + csw;
      gload16(Kb + kg, kbuf + t * 8);
      gload16(Kb + kg + 32 * 1024, kbuf + 2048 + t * 8);
      gload16(SPb + kg, skbuf + t * 8);
      gload16(SPb + kg + 32 * 1024, skbuf + 2048 + t * 8);
      const size_t vg = ((size_t)((b * 16 + h) * 64 + srow)) * 1024 + j0 + csw;
      gload16(Vt + vg, vbuf + t * 8);
      gload16(Vt + vg + 32 * 1024, vbuf + 2048 + t * 8);
    }
    __syncthreads();

    // ---- S^T: mfma(K-rows, Q-cols) -> C[j=ni*16+lq*4+r][i=lr] ------------
    f4v sa[4], ssa[4];
#pragma unroll
    for (int ni = 0; ni < 4; ++ni) { sa[ni] = fz; ssa[ni] = fz; }
#pragma unroll
    for (int ks = 0; ks < 2; ++ks) {
#pragma unroll
      for (int ni = 0; ni < 4; ++ni) {
        const int off = (ni * 16 + lr) * 64 + (((ks * 4 + lq) ^ rx) * 8);
        const s8v kf = *(const s8v*)(kbuf + off);
        sa[ni] = __builtin_amdgcn_mfma_f32_16x16x32_bf16(kf, qf[ks], sa[ni], 0, 0, 0);
        const s8v skf = *(const s8v*)(skbuf + off);
        ssa[ni] = __builtin_amdgcn_mfma_f32_16x16x32_bf16(skf, sf[ks], ssa[ni], 0, 0, 0);
      }
    }

    // ---- score modifiers + exp (no max subtraction) ----------------------
    const int D0 = iqw - j0;  // i - j = D0 + lr - j_loc
    float pv[4][4];
    if (jc < qt) {            // strictly below diagonal: i > j
      const float EA = K0 * fexp2(-c2 * (float)(D0 + lr));
#pragma unroll
      for (int ni = 0; ni < 4; ++ni)
#pragma unroll
        for (int r = 0; r < 4; ++r) {
          const float t1 = fmaf(ssa[ni][r], 0.125f, 1.0f);
          const float e = fexp2(sa[ni][r] * cN[ni] * cR[r] * EA * t1);
          pv[ni][r] = e;
          lacc[ni] += e;
        }
    } else if (jc > qt) {     // strictly above diagonal: i < j
      const float EAi = K0 * fexp2(c2 * (float)(D0 + lr));
#pragma unroll
      for (int ni = 0; ni < 4; ++ni)
#pragma unroll
        for (int r = 0; r < 4; ++r) {
          const float t1 = fmaf(ssa[ni][r], 0.125f, 1.0f);
          const float e = fexp2(sa[ni][r] * cNi[ni] * cRi[r] * EAi * t1);
          pv[ni][r] = e;
          lacc[ni] += e;
        }
    } else {                  // diagonal chunk: per-element side select
      const float EA  = K0 * fexp2(-c2 * (float)(D0 + lr));
      const float EAi = K0 * fexp2(c2 * (float)(D0 + lr));
#pragma unroll
      for (int ni = 0; ni < 4; ++ni)
#pragma unroll
        for (int r = 0; r < 4; ++r) {
          const int jloc = ni * 16 + lq * 4 + r;
          const float fb = cN[ni] * cR[r] * EA;
          const float fa = cNi[ni] * cRi[r] * EAi;
          const float f = (D0 + lr >= jloc) ? fb : fa;
          const float t1 = fmaf(ssa[ni][r], 0.125f, 1.0f);
          const float e = fexp2(sa[ni][r] * f * t1);
          pv[ni][r] = e;
          lacc[ni] += e;
        }
    }

    // ---- P[i][j] to LDS (b64 writes, XOR-swizzled chunks) ----------------
#pragma unroll
    for (int ni = 0; ni < 4; ++ni) {
      const int phys = (ni * 2 + (lq >> 1)) ^ rx;
      uint2 p2;
      p2.x = pk2(pv[ni][0], pv[ni][1]);
      p2.y = pk2(pv[ni][2], pv[ni][3]);
      *(uint2*)(pw + lr * 64 + phys * 8 + (lq & 1) * 4) = p2;
    }

    // ---- O^T += V^T @ P^T; vs += V^T @ ones (near-V column sums) ---------
#pragma unroll
    for (int ks = 0; ks < 2; ++ks) {
      const s8v pf = *(const s8v*)(pw + lr * 64 + (((ks * 4 + lq) ^ rx) * 8));
#pragma unroll
      for (int nd = 0; nd < 4; ++nd) {
        const int off = (nd * 16 + lr) * 64 + (((ks * 4 + lq) ^ rx) * 8);
        const s8v vf = *(const s8v*)(vbuf + off);
        oacc[nd] = __builtin_amdgcn_mfma_f32_16x16x32_bf16(vf, pf, oacc[nd], 0, 0, 0);
        vs[nd] = __builtin_amdgcn_mfma_f32_16x16x32_bf16(vf, ones, vs[nd], 0, 0, 0);
      }
    }
  }

  // ---- far field: oacc += Vtot - nearV; l += 64*farCnt; store ------------
  float ls = (lacc[0] + lacc[1]) + (lacc[2] + lacc[3]);
  ls += __shfl_xor(ls, 16);
  ls += __shfl_xor(ls, 32);
  ls += 64.0f * (float)farCnt;
  const float inv = 1.0f / ls;
  const float* vt0 = Vtot + (size_t)(b * 16 + h) * 64;
  const size_t orow = ((size_t)(b * 1024 + qt * 64 + w * 16 + lr)) * 1024 + h * 64;
#pragma unroll
  for (int nd = 0; nd < 4; ++nd) {
    const float4 vt4 = *(const float4*)(vt0 + nd * 16 + lq * 4);
    float o0 = (oacc[nd][0] + vt4.x - vs[nd][0]) * inv;
    float o1 = (oacc[nd][1] + vt4.y - vs[nd][1]) * inv;
    float o2 = (oacc[nd][2] + vt4.z - vs[nd][2]) * inv;
    float o3 = (oacc[nd][3] + vt4.w - vs[nd][3]) * inv;
    uint2 o;
    o.x = pk2r(o0, o1);
    o.y = pk2r(o2, o3);
    *(uint2*)(CTXb + orow + nd * 16 + lq * 4) = o;
  }
}

}  // namespace

extern "C" void kernel_launch(void* const* d_in, const int* in_sizes, int n_in,
                              void* d_out, int out_size, void* d_ws, size_t ws_size,
                              hipStream_t stream) {
  const float* x      = (const float*)d_in[0];
  const float* spikes = (const float*)d_in[1];
  const float* mem    = (const float*)d_in[2];
  const float* Wq     = (const float*)d_in[3];
  const float* bq     = (const float*)d_in[4];
  const float* Wk     = (const float*)d_in[5];
  const float* bk     = (const float*)d_in[6];
  const float* Wv     = (const float*)d_in[7];
  const float* bv     = (const float*)d_in[8];
  const float* Wo     = (const float*)d_in[9];
  const float* bo     = (const float*)d_in[10];
  const float* tau    = (const float*)d_in[11];
  const float* Wg     = (const float*)d_in[12];
  const float* bg     = (const float*)d_in[13];
  float* out = (float*)d_out;

  uint8_t* w8 = (uint8_t*)d_ws;
  u16* spb  = (u16*)(w8);                 // 8 MB
  u16* xb   = (u16*)(w8 + (8u << 20));    // 8 MB
  u16* Wqb  = (u16*)(w8 + (16u << 20));   // 2 MB
  u16* Wkb  = (u16*)(w8 + (18u << 20));   // 2 MB
  u16* Wvb  = (u16*)(w8 + (20u << 20));   // 2 MB
  u16* Wob  = (u16*)(w8 + (22u << 20));   // 2 MB
  u16* Wgb  = (u16*)(w8 + (24u << 20));   // 4 MB
  u16* Qb   = (u16*)(w8 + (28u << 20));   // 8 MB
  u16* Kb   = (u16*)(w8 + (36u << 20));   // 8 MB
  u16* Vt   = (u16*)(w8 + (44u << 20));   // 8 MB  [b,h,d,s]
  u16* CTXb = (u16*)(w8 + (52u << 20));   // 8 MB
  float* Vtot = (float*)(w8 + (60u << 20));  // 16 KB
  u16* memb = (u16*)d_out;  // 8 MB of the 16 MB fp32 out buffer; dead until
                            // the final out_gemm overwrites it
  u16* gctx = xb;           // x dead after QKV

  // 1) bf16 conversions (18 jobs) + Vtot zeroing (4 spare blocks)
  constexpr size_t QE = 262144 * 4;  // elements per job
  CvtArgs ca;
  for (int q = 0; q < 4; ++q) ca.j[q]     = {x + q * QE,      xb + q * QE};
  for (int q = 0; q < 4; ++q) ca.j[4 + q] = {spikes + q * QE, spb + q * QE};
  for (int q = 0; q < 4; ++q) ca.j[8 + q] = {mem + q * QE,    memb + q * QE};
  ca.j[12] = {Wq, Wqb};
  ca.j[13] = {Wk, Wkb};
  ca.j[14] = {Wv, Wvb};
  ca.j[15] = {Wo, Wob};
  ca.j[16] = {Wg, Wgb};
  ca.j[17] = {Wg + QE, Wgb + QE};
  ca.vz = Vtot;
  cvt_kernel<<<dim3(1024, 18), 256, 0, stream>>>(ca);

  // 2) FUSED QKV projection (round-5 version, fastest qkv measured)
  qkv_gemm<<<dim3(16, 32), 384, 0, stream>>>(xb, Wqb, Wkb, Wvb, bq, bk, bv, memb,
                                             Qb, Kb, Vt, Vtot);
  // 3) flash attention (near chunks + far-field closed form, XCD swizzle)
  attn_mfma<<<dim3(1024), 256, 0, stream>>>(Qb, Kb, spb, Vt, tau, Vtot, CTXb);
  // 4) dendritic gate (K=2048 concat; mem-bf16 lives in d_out) -- v1 gemm64
  gemm64<1><<<dim3(8, 64), 256, 0, stream>>>(CTXb, memb, Wgb, bg, gctx, nullptr, 2048);
  // 5) output projection (fp32 out; overwrites memb region last)
  gemm64<0><<<dim3(8, 64), 256, 0, stream>>>(gctx, nullptr, Wob, bo, nullptr, out, 1024);
}